// Round 1
// baseline (46.284 us; speedup 1.0000x reference)
//
#include <hip/hip_runtime.h>

// ImagePool steady-state: resolve sequential pool mutation on indices only,
// then do a single parallel gather-copy of image data.
//
// Semantics (per reference):
//   for i in 0..N-1 (sequential):
//     if swap_mask[i]==1: out[i] = pool[idx[i]]; pool[idx[i]] = inputs[i]
//     else:               out[i] = inputs[i]
//
// Resolved: out[i] = inputs[i]                      if swap_mask[i]==0
//           out[i] = inputs[last prev swapper p with idx[p]==idx[i]]  if exists
//           out[i] = pool[idx[i]]                   otherwise

#define NP 128      // N images
#define CAPP 50     // pool capacity
#define IMG_FLOATS (256 * 256 * 3)   // 196608 floats per image
#define IMG_F4 (IMG_FLOATS / 4)      // 49152 float4 per image

__global__ void build_src_kernel(const int* __restrict__ swap_mask,
                                 const int* __restrict__ idx,
                                 int* __restrict__ src) {
    __shared__ int s_mask[NP];
    __shared__ int s_idx[NP];
    __shared__ int s_src[NP];
    __shared__ int s_last[CAPP];

    int t = threadIdx.x;
    if (t < NP) {
        s_mask[t] = swap_mask[t];
        s_idx[t]  = idx[t];
    }
    if (t < CAPP) s_last[t] = -1;
    __syncthreads();

    if (t == 0) {
        // Tiny sequential scan in LDS: 128 iterations.
        for (int i = 0; i < NP; ++i) {
            int j = s_idx[i];
            if (s_mask[i] == 1) {
                int lw = s_last[j];
                s_src[i] = (lw >= 0) ? lw : (NP + j);  // inputs[lw] or pool[j]
                s_last[j] = i;
            } else {
                s_src[i] = i;                          // inputs[i]
            }
        }
    }
    __syncthreads();
    if (t < NP) src[t] = s_src[t];
}

__global__ void gather_copy_kernel(const float4* __restrict__ inputs,
                                   const float4* __restrict__ pool,
                                   const int* __restrict__ src,
                                   float4* __restrict__ out) {
    const int img = blockIdx.y;
    const int t = blockIdx.x * blockDim.x + threadIdx.x;  // 0 .. IMG_F4-1
    const int s = src[img];  // L2-cached broadcast; negligible
    const float4* base = (s < NP)
        ? (inputs + (size_t)s * IMG_F4)
        : (pool + (size_t)(s - NP) * IMG_F4);
    out[(size_t)img * IMG_F4 + t] = base[t];
}

extern "C" void kernel_launch(void* const* d_in, const int* in_sizes, int n_in,
                              void* d_out, int out_size, void* d_ws, size_t ws_size,
                              hipStream_t stream) {
    const float* inputs    = (const float*)d_in[0];  // (128, 256, 256, 3) f32
    const float* pool      = (const float*)d_in[1];  // (50, 256, 256, 3) f32
    const int*   swap_mask = (const int*)d_in[2];    // (128,)
    const int*   idx       = (const int*)d_in[3];    // (128,)
    float* out = (float*)d_out;

    int* src = (int*)d_ws;  // 128 ints of scratch

    build_src_kernel<<<1, 128, 0, stream>>>(swap_mask, idx, src);

    dim3 grid(IMG_F4 / 256, NP);  // (192, 128)
    gather_copy_kernel<<<grid, 256, 0, stream>>>(
        (const float4*)inputs, (const float4*)pool, src, (float4*)out);
}

// Round 3
// 35.381 us; speedup vs baseline: 1.3082x; 1.3082x over previous
//
#include <hip/hip_runtime.h>

// ImagePool steady-state, fully fused single kernel.
//
// Semantics (per reference, sequential over i):
//   if swap_mask[i]==1: out[i] = pool[idx[i]]; pool[idx[i]] = inputs[i]
//   else:               out[i] = inputs[i]
//
// Resolved source for out[img]:
//   mask==0            -> inputs[img]
//   mask==1, exists p  -> inputs[p], p = max{p<img : mask[p]==1 && idx[p]==idx[img]}
//   mask==1, no p      -> pool[idx[img]]
//
// The "max p" is computed per block with a 2-wave __ballot + find-last-set —
// O(1), no scan kernel, no workspace, no extra launch.

#define NP 128      // batch size
#define CAPP 50     // pool capacity
#define IMG_FLOATS (256 * 256 * 3)     // 196608 floats per image
#define IMG_F4 (IMG_FLOATS / 4)        // 49152 float4 per image
#define CHUNK 12                       // float4 per thread
#define BLOCKS_PER_IMG (IMG_F4 / (256 * CHUNK))  // 16

// Native vector type — __builtin_nontemporal_store requires a plain
// scalar/vector, not HIP_vector_type<float,4>.
typedef float f32x4 __attribute__((ext_vector_type(4)));

__global__ __launch_bounds__(256) void pool_gather_kernel(
    const f32x4* __restrict__ inputs,
    const f32x4* __restrict__ pool,
    const int* __restrict__ swap_mask,
    const int* __restrict__ idx,
    f32x4* __restrict__ out)
{
    const int img = blockIdx.y;
    const int t = threadIdx.x;

    __shared__ unsigned long long bal[2];
    __shared__ int s_src;

    // --- resolve source image index (all 256 threads, ~20 cycles) ---
    const int target = idx[img];
    // t < img (< 128) guards the swap_mask/idx reads in-bounds.
    const bool valid = (t < img) && (swap_mask[t] == 1) && (idx[t] == target);
    const unsigned long long m = __ballot(valid);
    if (t == 0)  bal[0] = m;   // wave 0: candidates 0..63
    if (t == 64) bal[1] = m;   // wave 1: candidates 64..127
    __syncthreads();
    if (t == 0) {
        int s;
        if (swap_mask[img] == 1) {
            const unsigned long long b1 = bal[1], b0 = bal[0];
            if (b1)      s = 64 + (63 - __clzll(b1));   // last writer in 64..127
            else if (b0) s = 63 - __clzll(b0);          // last writer in 0..63
            else         s = NP + target;               // original pool slot
        } else {
            s = img;                                    // not swapped
        }
        s_src = s;
    }
    __syncthreads();

    // --- bulk copy: 12 float4 per thread, 48 KB per block ---
    const int s = s_src;
    const f32x4* __restrict__ base = (s < NP)
        ? inputs + (size_t)s * IMG_F4
        : pool + (size_t)(s - NP) * IMG_F4;
    f32x4* __restrict__ o = out + (size_t)img * IMG_F4;

    const int start = blockIdx.x * (256 * CHUNK) + t;
#pragma unroll
    for (int k = 0; k < CHUNK; ++k) {
        const int off = start + k * 256;
        const f32x4 v = base[off];
        // out is write-once, never re-read: keep it out of L2/L3 so the
        // read stream (inputs+pool, 140 MB, L3-cacheable) stays resident.
        __builtin_nontemporal_store(v, &o[off]);
    }
}

extern "C" void kernel_launch(void* const* d_in, const int* in_sizes, int n_in,
                              void* d_out, int out_size, void* d_ws, size_t ws_size,
                              hipStream_t stream) {
    const float* inputs    = (const float*)d_in[0];  // (128, 256, 256, 3) f32
    const float* pool      = (const float*)d_in[1];  // (50, 256, 256, 3) f32
    const int*   swap_mask = (const int*)d_in[2];    // (128,)
    const int*   idx       = (const int*)d_in[3];    // (128,)
    float* out = (float*)d_out;

    dim3 grid(BLOCKS_PER_IMG, NP);  // (16, 128) = 2048 blocks
    pool_gather_kernel<<<grid, 256, 0, stream>>>(
        (const f32x4*)inputs, (const f32x4*)pool, swap_mask, idx, (f32x4*)out);
}

// Round 4
// 35.324 us; speedup vs baseline: 1.3103x; 1.0016x over previous
//
#include <hip/hip_runtime.h>

// ImagePool steady-state, fully fused single kernel.
//
// Semantics (per reference, sequential over i):
//   if swap_mask[i]==1: out[i] = pool[idx[i]]; pool[idx[i]] = inputs[i]
//   else:               out[i] = inputs[i]
//
// Resolved source for out[img]:
//   mask==0            -> inputs[img]
//   mask==1, exists p  -> inputs[p], p = max{p<img : mask[p]==1 && idx[p]==idx[img]}
//   mask==1, no p      -> pool[idx[img]]
//
// All 128 sources are provably distinct -> exactly 100.7 MB read + 100.7 MB
// written, no duplicate traffic. Total footprint (inputs + live pool slots +
// out) ~= 240 MB < 256 MB Infinity Cache, so with CACHEABLE stores the output
// stays L3-resident dirty across graph replays and re-writes need no HBM
// writeback. (R3 lesson: nontemporal stores forced 98 MB/replay to HBM and
// made HBM the bottleneck.)

#define NP 128      // batch size
#define CAPP 50     // pool capacity
#define IMG_FLOATS (256 * 256 * 3)     // 196608 floats per image
#define IMG_F4 (IMG_FLOATS / 4)        // 49152 float4 per image
#define CHUNK 12                       // float4 per thread
#define BLOCKS_PER_IMG (IMG_F4 / (256 * CHUNK))  // 16

typedef float f32x4 __attribute__((ext_vector_type(4)));

__global__ __launch_bounds__(256) void pool_gather_kernel(
    const f32x4* __restrict__ inputs,
    const f32x4* __restrict__ pool,
    const int* __restrict__ swap_mask,
    const int* __restrict__ idx,
    f32x4* __restrict__ out)
{
    const int img = blockIdx.y;
    const int t = threadIdx.x;

    __shared__ unsigned long long bal[2];
    __shared__ int s_src;

    // --- resolve source image index (all 256 threads, ~20 cycles) ---
    const int target = idx[img];
    // t < img (< 128) guards the swap_mask/idx reads in-bounds.
    const bool valid = (t < img) && (swap_mask[t] == 1) && (idx[t] == target);
    const unsigned long long m = __ballot(valid);
    if (t == 0)  bal[0] = m;   // wave 0: candidates 0..63
    if (t == 64) bal[1] = m;   // wave 1: candidates 64..127
    __syncthreads();
    if (t == 0) {
        int s;
        if (swap_mask[img] == 1) {
            const unsigned long long b1 = bal[1], b0 = bal[0];
            if (b1)      s = 64 + (63 - __clzll(b1));   // last writer in 64..127
            else if (b0) s = 63 - __clzll(b0);          // last writer in 0..63
            else         s = NP + target;               // original pool slot
        } else {
            s = img;                                    // not swapped
        }
        s_src = s;
    }
    __syncthreads();

    // --- bulk copy: 12 float4 per thread, 48 KB per block ---
    const int s = s_src;
    const f32x4* __restrict__ base = (s < NP)
        ? inputs + (size_t)s * IMG_F4
        : pool + (size_t)(s - NP) * IMG_F4;
    f32x4* __restrict__ o = out + (size_t)img * IMG_F4;

    const int start = blockIdx.x * (256 * CHUNK) + t;
#pragma unroll
    for (int k = 0; k < CHUNK; ++k) {
        const int off = start + k * 256;
        o[off] = base[off];   // cacheable store: let L3 keep it resident
    }
}

extern "C" void kernel_launch(void* const* d_in, const int* in_sizes, int n_in,
                              void* d_out, int out_size, void* d_ws, size_t ws_size,
                              hipStream_t stream) {
    const float* inputs    = (const float*)d_in[0];  // (128, 256, 256, 3) f32
    const float* pool      = (const float*)d_in[1];  // (50, 256, 256, 3) f32
    const int*   swap_mask = (const int*)d_in[2];    // (128,)
    const int*   idx       = (const int*)d_in[3];    // (128,)
    float* out = (float*)d_out;

    dim3 grid(BLOCKS_PER_IMG, NP);  // (16, 128) = 2048 blocks
    pool_gather_kernel<<<grid, 256, 0, stream>>>(
        (const f32x4*)inputs, (const f32x4*)pool, swap_mask, idx, (f32x4*)out);
}